// Round 7
// baseline (1324.300 us; speedup 1.0000x reference)
//
#include <hip/hip_runtime.h>
#include <math.h>

static constexpr int Bc    = 4;
static constexpr int Tc    = 2048;
static constexpr int HIDc  = 1024;
static constexpr int NHc   = 8;
static constexpr int HDc   = 128;
static constexpr int Mrows = Bc * Tc;          // 8192
static constexpr int INTERc= 2816;
static constexpr int CH    = 64;               // scan chunk length
static constexpr int NC    = Tc / CH;          // 32 chunks

typedef _Float16 f16;
typedef __attribute__((ext_vector_type(8))) _Float16 f16x8;
typedef __attribute__((ext_vector_type(4))) float f32x4;
typedef unsigned short u16;

union H8 { f16 h[8]; int4 v; u16 u[8]; };
union H4 { f16 h[4]; int2 v; u16 u[4]; };
union F4 { float4 v; float a[4]; };

static __device__ __forceinline__ float sigm(float x) { return 1.0f / (1.0f + expf(-x)); }
static __device__ __forceinline__ float silu(float x) { return x * sigm(x); }
static __device__ __forceinline__ float elu1(float x) { return x > 0.0f ? x + 1.0f : expf(x); }

static __device__ __forceinline__ float h2f(u16 u){ f16 h; __builtin_memcpy(&h,&u,2); return (float)h; }
static __device__ __forceinline__ u16 f2h(float x){ f16 h=(f16)x; u16 u; __builtin_memcpy(&u,&h,2); return u; }
static __device__ __forceinline__ float rec2(u16 h, u16 l){ return h2f(h) + h2f(l); }
static __device__ __forceinline__ void fsplit(float v, u16& h, u16& l){ h = f2h(v); l = f2h(v - h2f(h)); }

// async global->LDS, 16B/lane; LDS dest = wave-uniform base + lane*16
static __device__ __forceinline__ void gld16(const u16* g, u16* l)
{
    __builtin_amdgcn_global_load_lds((const __attribute__((address_space(1))) void*)g,
                                     (__attribute__((address_space(3))) void*)l,
                                     16, 0, 0);
}

// ---------------------------------------------------------------------------
__global__ __launch_bounds__(256) void wcvt_k(const float* __restrict__ src,
                                              u16* __restrict__ dst, int n8)
{
    const int i = blockIdx.x * 256 + threadIdx.x;
    if (i >= n8) return;
    F4 a, b; a.v = ((const float4*)src)[i * 2]; b.v = ((const float4*)src)[i * 2 + 1];
    H8 o;
    #pragma unroll
    for (int u = 0; u < 4; u++) { o.h[u] = (f16)a.a[u]; o.h[4 + u] = (f16)b.a[u]; }
    ((int4*)dst)[i] = o.v;
}

// ---------------------------------------------------------------------------
template<int INPAIR>
__global__ __launch_bounds__(256) void rmsnorm_k(const float* __restrict__ xf,
                                                 const u16* __restrict__ xhi,
                                                 const u16* __restrict__ xlo,
                                                 const float* __restrict__ w,
                                                 u16* __restrict__ ohi,
                                                 u16* __restrict__ olo)
{
    const int row = blockIdx.x;
    const int tid = threadIdx.x;
    const size_t off = (size_t)row * HIDc + tid * 4;
    float xv[4];
    if constexpr (INPAIR) {
        H4 H, L;
        H.v = *(const int2*)(xhi + off);
        L.v = *(const int2*)(xlo + off);
        #pragma unroll
        for (int u = 0; u < 4; u++) xv[u] = (float)H.h[u] + (float)L.h[u];
    } else {
        F4 f; f.v = *(const float4*)(xf + off);
        #pragma unroll
        for (int u = 0; u < 4; u++) xv[u] = f.a[u];
    }
    float ss = xv[0]*xv[0] + xv[1]*xv[1] + xv[2]*xv[2] + xv[3]*xv[3];
    #pragma unroll
    for (int o = 32; o > 0; o >>= 1) ss += __shfl_xor(ss, o);
    __shared__ float sred[4];
    if ((tid & 63) == 0) sred[tid >> 6] = ss;
    __syncthreads();
    const float tot = sred[0] + sred[1] + sred[2] + sred[3];
    const float scale = rsqrtf(tot * (1.0f / (float)HIDc) + 1e-6f);
    F4 wv; wv.v = *(const float4*)(w + tid * 4);
    H4 OH, OL;
    #pragma unroll
    for (int u = 0; u < 4; u++) {
        u16 hh, ll; fsplit(xv[u] * scale * wv.a[u], hh, ll);
        OH.u[u] = hh; OL.u[u] = ll;
    }
    *(int2*)(ohi + off) = OH.v;
    *(int2*)(olo + off) = OL.v;
}

// ---------------------------------------------------------------------------
__global__ __launch_bounds__(256) void conv_k(const u16* __restrict__ hhi,
                                              const u16* __restrict__ hlo,
                                              const float* __restrict__ cw,
                                              const float* __restrict__ cb,
                                              u16* __restrict__ ohi,
                                              u16* __restrict__ olo)
{
    const int row = blockIdx.x;
    const int t   = row & (Tc - 1);
    const int ch4 = threadIdx.x * 4;
    const float* wp = cw + (size_t)ch4 * 4;
    F4 bias; bias.v = *(const float4*)(cb + ch4);
    F4 acc;
    #pragma unroll
    for (int u = 0; u < 4; u++) acc.a[u] = bias.a[u];
    #pragma unroll
    for (int j = 0; j < 4; j++) {
        const int tt = t - 3 + j;
        if (tt >= 0) {
            const size_t off = ((size_t)row + j - 3) * HIDc + ch4;
            H4 H, L;
            H.v = *(const int2*)(hhi + off);
            L.v = *(const int2*)(hlo + off);
            #pragma unroll
            for (int u = 0; u < 4; u++) acc.a[u] += ((float)H.h[u] + (float)L.h[u]) * wp[u * 4 + j];
        }
    }
    H4 OH, OL;
    #pragma unroll
    for (int u = 0; u < 4; u++) {
        u16 hh, ll; fsplit(silu(acc.a[u]), hh, ll);
        OH.u[u] = hh; OL.u[u] = ll;
    }
    const size_t off = (size_t)row * HIDc + ch4;
    *(int2*)(ohi + off) = OH.v;
    *(int2*)(olo + off) = OL.v;
}

// ---------------------------------------------------------------------------
__global__ __launch_bounds__(64) void scan1_k(u16* __restrict__ khi, u16* __restrict__ klo,
                                              const u16* __restrict__ vhi, const u16* __restrict__ vlo,
                                              u16* __restrict__ shi, u16* __restrict__ slo,
                                              const float* __restrict__ dp)
{
    const int bid = blockIdx.x;
    const int c   = bid & (NC - 1);
    const int bh  = bid >> 5;
    const int b   = bh >> 3, hh = bh & 7;
    const int lane = threadIdx.x;
    const float dec = sigm(dp[hh]);
    const size_t base = (size_t)b * Tc * HIDc + (size_t)(c * CH) * HIDc + hh * HDc + lane * 2;
    float skv0 = 0.f, skv1 = 0.f, sks0 = 0.f, sks1 = 0.f;
    for (int t = 0; t < CH; t++) {
        const size_t p = base + (size_t)t * HIDc;
        const unsigned kh = *(const unsigned*)(khi + p);
        const unsigned kl = *(const unsigned*)(klo + p);
        const unsigned vh = *(const unsigned*)(vhi + p);
        const unsigned vl = *(const unsigned*)(vlo + p);
        const float kx = elu1(rec2((u16)kh, (u16)kl));
        const float ky = elu1(rec2((u16)(kh >> 16), (u16)(kl >> 16)));
        const float vx = rec2((u16)vh, (u16)vl);
        const float vy = rec2((u16)(vh >> 16), (u16)(vl >> 16));
        skv0 = dec * skv0 + kx * vx;
        skv1 = dec * skv1 + ky * vy;
        sks0 = dec * sks0 + kx;
        sks1 = dec * sks1 + ky;
        u16 h0, l0, h1, l1;
        fsplit(skv0, h0, l0); fsplit(skv1, h1, l1);
        *(unsigned*)(khi + p) = (unsigned)h0 | ((unsigned)h1 << 16);
        *(unsigned*)(klo + p) = (unsigned)l0 | ((unsigned)l1 << 16);
        fsplit(sks0, h0, l0); fsplit(sks1, h1, l1);
        *(unsigned*)(shi + p) = (unsigned)h0 | ((unsigned)h1 << 16);
        *(unsigned*)(slo + p) = (unsigned)l0 | ((unsigned)l1 << 16);
    }
}

// ---------------------------------------------------------------------------
__global__ __launch_bounds__(64) void scan2_k(u16* __restrict__ qhi, u16* __restrict__ qlo,
                                              const u16* __restrict__ skvhi, const u16* __restrict__ skvlo,
                                              const u16* __restrict__ skshi, const u16* __restrict__ skslo,
                                              const float* __restrict__ dp)
{
    const int bid = blockIdx.x;
    const int c   = bid & (NC - 1);
    const int bh  = bid >> 5;
    const int b   = bh >> 3, hh = bh & 7;
    const int lane = threadIdx.x;
    const float dec = sigm(dp[hh]);
    float dCH = dec;
    #pragma unroll
    for (int i = 0; i < 6; i++) dCH *= dCH;      // dec^64
    const size_t rowbase = (size_t)b * Tc * HIDc + hh * HDc + lane * 2;

    float ckv0 = 0.f, ckv1 = 0.f, cks0 = 0.f, cks1 = 0.f;
    for (int j = 0; j < c; j++) {
        const size_t p = rowbase + (size_t)(j * CH + CH - 1) * HIDc;
        const unsigned ah = *(const unsigned*)(skvhi + p);
        const unsigned al = *(const unsigned*)(skvlo + p);
        const unsigned bh2 = *(const unsigned*)(skshi + p);
        const unsigned bl2 = *(const unsigned*)(skslo + p);
        ckv0 = ckv0 * dCH + rec2((u16)ah, (u16)al);
        ckv1 = ckv1 * dCH + rec2((u16)(ah >> 16), (u16)(al >> 16));
        cks0 = cks0 * dCH + rec2((u16)bh2, (u16)bl2);
        cks1 = cks1 * dCH + rec2((u16)(bh2 >> 16), (u16)(bl2 >> 16));
    }

    const size_t cbase = rowbase + (size_t)(c * CH) * HIDc;
    float pw = dec;
    for (int t = 0; t < CH; t++) {
        const size_t p = cbase + (size_t)t * HIDc;
        const unsigned qh = *(const unsigned*)(qhi + p);
        const unsigned ql = *(const unsigned*)(qlo + p);
        const unsigned ah = *(const unsigned*)(skvhi + p);
        const unsigned al = *(const unsigned*)(skvlo + p);
        const unsigned bh2 = *(const unsigned*)(skshi + p);
        const unsigned bl2 = *(const unsigned*)(skslo + p);
        const float qx = elu1(rec2((u16)qh, (u16)ql));
        const float qy = elu1(rec2((u16)(qh >> 16), (u16)(ql >> 16)));
        const float skv0 = rec2((u16)ah, (u16)al) + pw * ckv0;
        const float skv1 = rec2((u16)(ah >> 16), (u16)(al >> 16)) + pw * ckv1;
        const float sks0 = rec2((u16)bh2, (u16)bl2) + pw * cks0;
        const float sks1 = rec2((u16)(bh2 >> 16), (u16)(bl2 >> 16)) + pw * cks1;
        float part = qx * sks0 + qy * sks1;
        #pragma unroll
        for (int o = 32; o > 0; o >>= 1) part += __shfl_xor(part, o);
        const float inv = 1.0f / fmaxf(part, 1e-6f);
        u16 h0, l0, h1, l1;
        fsplit(qx * skv0 * inv, h0, l0);
        fsplit(qy * skv1 * inv, h1, l1);
        *(unsigned*)(qhi + p) = (unsigned)h0 | ((unsigned)h1 << 16);
        *(unsigned*)(qlo + p) = (unsigned)l0 | ((unsigned)l1 << 16);
        pw *= dec;
    }
}

// ---------------------------------------------------------------------------
// fp16-pair MFMA GEMM, BK=64, global_load_lds staging, XCD-swizzled 1-D grid.
// MODE 0: C = acc  | 1: silu | 2: pair RMW mul | 3: sigmoid-gate(E0,E1)+bias
// MODE 4: sigmoid-gate, A split at kSplit; C = E0f + g*E1 + (1-g)*E2
// MODE 5: qkv scatter (q->Chi/Clo, k->E0, v->E1, plane from n0>>10)
// MODE 6: Cout = rec(Cpair) + acc (fp32 out)
// ---------------------------------------------------------------------------
template<int MODE, int PRE>
__global__ __launch_bounds__(256) void gemm_f16_k(
    const u16* __restrict__ Ahi, const u16* __restrict__ Alo,
    const u16* __restrict__ A2hi, const u16* __restrict__ A2lo, int lda,
    const u16* __restrict__ Wh, const float* __restrict__ Wf,
    float* __restrict__ Cout,
    u16* __restrict__ Chi, u16* __restrict__ Clo, int ldc,
    int K, int kSplit, int nx,
    const float* __restrict__ bias,
    const float* __restrict__ E0f,
    const u16* __restrict__ E0hi, const u16* __restrict__ E0lo, int ldE0,
    const u16* __restrict__ E1hi, const u16* __restrict__ E1lo, int ldE1,
    const u16* __restrict__ E2hi, const u16* __restrict__ E2lo, int ldE2)
{
    __shared__ __align__(16) u16 Ah[8][128][8];
    __shared__ __align__(16) u16 Al[8][128][8];
    __shared__ __align__(16) u16 Bs[8][128][8];

    const int tid  = threadIdx.x;
    const int lane = tid & 63;
    const int wv   = tid >> 6;
    const int wr   = wv >> 1, wc = wv & 1;
    const int lr   = lane & 15, lk = lane >> 4;

    const int cpx = gridDim.x >> 3;
    int bid = blockIdx.x;
    bid = (bid & 7) * cpx + (bid >> 3);
    const int n0 = (bid % nx) * 128;
    const int m0 = (bid / nx) * 128;

    f32x4 acc[4][4];
    #pragma unroll
    for (int i = 0; i < 4; i++)
        #pragma unroll
        for (int j = 0; j < 4; j++)
            acc[i][j] = (f32x4){0.f, 0.f, 0.f, 0.f};

    for (int k0 = 0; k0 < K; k0 += 64) {
        const u16* ah = Ahi; const u16* al = Alo; int kb = k0;
        if constexpr (MODE == 4) {
            if (k0 >= kSplit) { ah = A2hi; al = A2lo; kb = k0 - kSplit; }
        }
        F4 wreg[8];
        if constexpr (!PRE) {
            #pragma unroll
            for (int q = 0; q < 2; q++) {
                const float* wp0 = Wf + (size_t)(n0 + lane) * K + k0 + (2 * wv + q) * 8;
                const float* wp1 = wp0 + (size_t)64 * K;
                wreg[q * 4 + 0].v = *(const float4*)(wp0);
                wreg[q * 4 + 1].v = *(const float4*)(wp0 + 4);
                wreg[q * 4 + 2].v = *(const float4*)(wp1);
                wreg[q * 4 + 3].v = *(const float4*)(wp1 + 4);
            }
        }
        __syncthreads();   // previous iteration's LDS reads done
        #pragma unroll
        for (int q = 0; q < 2; q++) {
            const int cc = 2 * wv + q;
            const size_t a0 = (size_t)(m0 + lane) * lda + kb + cc * 8;
            gld16(ah + a0, &Ah[cc][0][0]);
            gld16(ah + a0 + (size_t)64 * lda, &Ah[cc][64][0]);
            gld16(al + a0, &Al[cc][0][0]);
            gld16(al + a0 + (size_t)64 * lda, &Al[cc][64][0]);
            if constexpr (PRE) {
                const size_t w0 = (size_t)(n0 + lane) * K + k0 + cc * 8;
                gld16(Wh + w0, &Bs[cc][0][0]);
                gld16(Wh + w0 + (size_t)64 * K, &Bs[cc][64][0]);
            } else {
                H8 W0, W1;
                #pragma unroll
                for (int e = 0; e < 8; e++) {
                    W0.h[e] = (f16)wreg[q * 4 + (e >> 2)].a[e & 3];
                    W1.h[e] = (f16)wreg[q * 4 + 2 + (e >> 2)].a[e & 3];
                }
                *(int4*)&Bs[cc][lane][0]      = W0.v;
                *(int4*)&Bs[cc][64 + lane][0] = W1.v;
            }
        }
        __syncthreads();
        #pragma unroll
        for (int ks = 0; ks < 2; ks++) {
            const int ck = ks * 4 + lk;
            f16x8 av[4], au[4], bv[4];
            #pragma unroll
            for (int fi = 0; fi < 4; fi++) {
                av[fi] = *(const f16x8*)&Ah[ck][wr * 64 + fi * 16 + lr][0];
                au[fi] = *(const f16x8*)&Al[ck][wr * 64 + fi * 16 + lr][0];
                bv[fi] = *(const f16x8*)&Bs[ck][wc * 64 + fi * 16 + lr][0];
            }
            #pragma unroll
            for (int i = 0; i < 4; i++)
                #pragma unroll
                for (int j = 0; j < 4; j++) {
                    acc[i][j] = __builtin_amdgcn_mfma_f32_16x16x32_f16(av[i], bv[j], acc[i][j], 0, 0, 0);
                    acc[i][j] = __builtin_amdgcn_mfma_f32_16x16x32_f16(au[i], bv[j], acc[i][j], 0, 0, 0);
                }
        }
    }

    // epilogue: C/D layout col=lane&15, row=(lane>>4)*4+reg
    u16* dsth = Chi; u16* dstl = Clo;
    int nbase = n0;
    if constexpr (MODE == 5) {
        const int plane = n0 >> 10;
        nbase = n0 & 1023;
        if (plane == 1)      { dsth = const_cast<u16*>(E0hi); dstl = const_cast<u16*>(E0lo); }
        else if (plane == 2) { dsth = const_cast<u16*>(E1hi); dstl = const_cast<u16*>(E1lo); }
    }
    #pragma unroll
    for (int i = 0; i < 4; i++) {
        #pragma unroll
        for (int j = 0; j < 4; j++) {
            #pragma unroll
            for (int v = 0; v < 4; v++) {
                const size_t r = (size_t)(m0 + wr * 64 + i * 16 + lk * 4 + v);
                const int c = nbase + wc * 64 + j * 16 + lr;
                const size_t idx = r * (size_t)ldc + c;
                float val = acc[i][j][v];
                if constexpr (MODE == 1) {
                    val = silu(val);
                } else if constexpr (MODE == 2) {
                    val = rec2(Chi[idx], Clo[idx]) * val;
                } else if constexpr (MODE == 3) {
                    const float g = sigm(val + bias[c]);
                    const size_t i0 = r * (size_t)ldE0 + c, i1 = r * (size_t)ldE1 + c;
                    val = g * rec2(E0hi[i0], E0lo[i0]) + (1.0f - g) * rec2(E1hi[i1], E1lo[i1]);
                } else if constexpr (MODE == 4) {
                    const float g = sigm(val);
                    const size_t i1 = r * (size_t)ldE1 + c, i2 = r * (size_t)ldE2 + c;
                    val = E0f[r * (size_t)ldE0 + c] + g * rec2(E1hi[i1], E1lo[i1])
                          + (1.0f - g) * rec2(E2hi[i2], E2lo[i2]);
                } else if constexpr (MODE == 6) {
                    Cout[idx] = rec2(Chi[idx], Clo[idx]) + val;
                    continue;
                }
                u16 hh, ll; fsplit(val, hh, ll);
                dsth[idx] = hh; dstl[idx] = ll;
            }
        }
    }
}

// ---------------------------------------------------------------------------
// Fused SwiGLU GEMM (PRE-only): u = silu(A@W1^T) * (A@W2^T), pair out.
// BK=64, dual accumulators, 128 MFMA per K-iter.
// ---------------------------------------------------------------------------
__global__ __launch_bounds__(256) void gemm_dual_k(
    const u16* __restrict__ Ahi, const u16* __restrict__ Alo, int lda,
    const u16* __restrict__ W1h, const u16* __restrict__ W2h,
    u16* __restrict__ Chi, u16* __restrict__ Clo, int ldc,
    int K, int nx)
{
    __shared__ __align__(16) u16 Ah[8][128][8];
    __shared__ __align__(16) u16 Al[8][128][8];
    __shared__ __align__(16) u16 B1[8][128][8];
    __shared__ __align__(16) u16 B2[8][128][8];

    const int tid  = threadIdx.x;
    const int lane = tid & 63;
    const int wv   = tid >> 6;
    const int wr   = wv >> 1, wc = wv & 1;
    const int lr   = lane & 15, lk = lane >> 4;

    const int cpx = gridDim.x >> 3;
    int bid = blockIdx.x;
    bid = (bid & 7) * cpx + (bid >> 3);
    const int n0 = (bid % nx) * 128;
    const int m0 = (bid / nx) * 128;

    f32x4 acc1[4][4], acc2[4][4];
    #pragma unroll
    for (int i = 0; i < 4; i++)
        #pragma unroll
        for (int j = 0; j < 4; j++) {
            acc1[i][j] = (f32x4){0.f, 0.f, 0.f, 0.f};
            acc2[i][j] = (f32x4){0.f, 0.f, 0.f, 0.f};
        }

    for (int k0 = 0; k0 < K; k0 += 64) {
        __syncthreads();
        #pragma unroll
        for (int q = 0; q < 2; q++) {
            const int cc = 2 * wv + q;
            const size_t a0 = (size_t)(m0 + lane) * lda + k0 + cc * 8;
            gld16(Ahi + a0, &Ah[cc][0][0]);
            gld16(Ahi + a0 + (size_t)64 * lda, &Ah[cc][64][0]);
            gld16(Alo + a0, &Al[cc][0][0]);
            gld16(Alo + a0 + (size_t)64 * lda, &Al[cc][64][0]);
            const size_t w0 = (size_t)(n0 + lane) * K + k0 + cc * 8;
            gld16(W1h + w0, &B1[cc][0][0]);
            gld16(W1h + w0 + (size_t)64 * K, &B1[cc][64][0]);
            gld16(W2h + w0, &B2[cc][0][0]);
            gld16(W2h + w0 + (size_t)64 * K, &B2[cc][64][0]);
        }
        __syncthreads();
        #pragma unroll
        for (int ks = 0; ks < 2; ks++) {
            const int ck = ks * 4 + lk;
            f16x8 av[4], au[4], b1[4], b2[4];
            #pragma unroll
            for (int fi = 0; fi < 4; fi++) {
                av[fi] = *(const f16x8*)&Ah[ck][wr * 64 + fi * 16 + lr][0];
                au[fi] = *(const f16x8*)&Al[ck][wr * 64 + fi * 16 + lr][0];
                b1[fi] = *(const f16x8*)&B1[ck][wc * 64 + fi * 16 + lr][0];
                b2[fi] = *(const f16x8*)&B2[ck][wc * 64 + fi * 16 + lr][0];
            }
            #pragma unroll
            for (int i = 0; i < 4; i++)
                #pragma unroll
                for (int j = 0; j < 4; j++) {
                    acc1[i][j] = __builtin_amdgcn_mfma_f32_16x16x32_f16(av[i], b1[j], acc1[i][j], 0, 0, 0);
                    acc1[i][j] = __builtin_amdgcn_mfma_f32_16x16x32_f16(au[i], b1[j], acc1[i][j], 0, 0, 0);
                    acc2[i][j] = __builtin_amdgcn_mfma_f32_16x16x32_f16(av[i], b2[j], acc2[i][j], 0, 0, 0);
                    acc2[i][j] = __builtin_amdgcn_mfma_f32_16x16x32_f16(au[i], b2[j], acc2[i][j], 0, 0, 0);
                }
        }
    }

    #pragma unroll
    for (int i = 0; i < 4; i++) {
        #pragma unroll
        for (int j = 0; j < 4; j++) {
            #pragma unroll
            for (int v = 0; v < 4; v++) {
                const size_t r = (size_t)(m0 + wr * 64 + i * 16 + lk * 4 + v);
                const int c = n0 + wc * 64 + j * 16 + lr;
                const size_t idx = r * (size_t)ldc + c;
                const float val = silu(acc1[i][j][v]) * acc2[i][j][v];
                u16 hh, ll; fsplit(val, hh, ll);
                Chi[idx] = hh; Clo[idx] = ll;
            }
        }
    }
}

template<int MODE>
static inline void launch_gemm(bool pre, int nblocks, int nx, hipStream_t stream,
    const u16* Ahi, const u16* Alo, const u16* A2hi, const u16* A2lo, int lda,
    const u16* Wh, const float* Wf,
    float* Cout, u16* Chi, u16* Clo, int ldc, int K, int kSplit,
    const float* bias, const float* E0f,
    const u16* E0hi, const u16* E0lo, int ldE0,
    const u16* E1hi, const u16* E1lo, int ldE1,
    const u16* E2hi, const u16* E2lo, int ldE2)
{
    if (pre)
        gemm_f16_k<MODE, 1><<<dim3(nblocks), dim3(256), 0, stream>>>(Ahi, Alo, A2hi, A2lo, lda, Wh, Wf,
            Cout, Chi, Clo, ldc, K, kSplit, nx, bias, E0f, E0hi, E0lo, ldE0, E1hi, E1lo, ldE1, E2hi, E2lo, ldE2);
    else
        gemm_f16_k<MODE, 0><<<dim3(nblocks), dim3(256), 0, stream>>>(Ahi, Alo, A2hi, A2lo, lda, Wh, Wf,
            Cout, Chi, Clo, ldc, K, kSplit, nx, bias, E0f, E0hi, E0lo, ldE0, E1hi, E1lo, ldE1, E2hi, E2lo, ldE2);
}

// ---------------------------------------------------------------------------
extern "C" void kernel_launch(void* const* d_in, const int* in_sizes, int n_in,
                              void* d_out, int out_size, void* d_ws, size_t ws_size,
                              hipStream_t stream)
{
    const float* x           = (const float*)d_in[0];
    const float* qkv_w       = (const float*)d_in[1];
    const float* out_proj_w  = (const float*)d_in[2];
    const float* out_gate_w  = (const float*)d_in[3];
    const float* out_gate_b  = (const float*)d_in[4];
    const float* decay_param = (const float*)d_in[5];
    const float* conv_w      = (const float*)d_in[6];
    const float* conv_b      = (const float*)d_in[7];
    const float* pw_w        = (const float*)d_in[8];
    const float* gate_w      = (const float*)d_in[9];
    const float* w1          = (const float*)d_in[10];
    const float* w2          = (const float*)d_in[11];
    const float* w3          = (const float*)d_in[12];
    const float* norm1_w     = (const float*)d_in[13];
    const float* norm2_w     = (const float*)d_in[14];
    float* OUT = (float*)d_out;

    float* ws = (float*)d_ws;
    const size_t S8 = (size_t)Mrows * HIDc;   // 8,388,608
    u16* P0h = (u16*)(ws + 0 * S8); u16* P0l = P0h + S8;
    u16* P1h = (u16*)(ws + 1 * S8); u16* P1l = P1h + S8;
    u16* P2h = (u16*)(ws + 2 * S8); u16* P2l = P2h + S8;
    u16* P3h = (u16*)(ws + 3 * S8); u16* P3l = P3h + S8;
    u16* OUTh = (u16*)OUT;          u16* OUTl = OUTh + S8;
    u16* T1h = P1h;                 u16* T1l = P1h + (size_t)Mrows * INTERc;

    constexpr size_t SZ_QKV  = (size_t)3 * HIDc * HIDc;
    constexpr size_t SZ_SQ   = (size_t)HIDc * HIDc;
    constexpr size_t SZ_GATE = (size_t)2 * HIDc * HIDc;
    constexpr size_t SZ_W1   = (size_t)INTERc * HIDc;
    constexpr size_t W_ELEMS = SZ_QKV + 3 * SZ_SQ + SZ_GATE + 3 * SZ_W1;  // 17,039,360
    const bool pre = (ws_size >= 4 * S8 * sizeof(float) + W_ELEMS * sizeof(u16));

    u16* wb   = (u16*)(ws + 4 * S8);
    u16* qkvH = wb;
    u16* pwH  = qkvH + SZ_QKV;
    u16* ogH  = pwH  + SZ_SQ;
    u16* opH  = ogH  + SZ_SQ;
    u16* gaH  = opH  + SZ_SQ;
    u16* w1H  = gaH  + SZ_GATE;
    u16* w2H  = w1H  + SZ_W1;
    u16* w3H  = w2H  + SZ_W1;

    const dim3 blk(256);
    const int nb8  = 8 * (Mrows / 128);    // 512
    const int nb22 = 22 * (Mrows / 128);   // 1408
    const int nb24 = 24 * (Mrows / 128);   // 1536
    const u16* nu = nullptr;

    if (pre) {
        wcvt_k<<<(int)(SZ_QKV / 8 / 256), blk, 0, stream>>>(qkv_w, qkvH, (int)(SZ_QKV / 8));
        wcvt_k<<<(int)(SZ_SQ  / 8 / 256), blk, 0, stream>>>(pw_w,  pwH,  (int)(SZ_SQ  / 8));
        wcvt_k<<<(int)(SZ_SQ  / 8 / 256), blk, 0, stream>>>(out_gate_w, ogH, (int)(SZ_SQ / 8));
        wcvt_k<<<(int)(SZ_SQ  / 8 / 256), blk, 0, stream>>>(out_proj_w, opH, (int)(SZ_SQ / 8));
        wcvt_k<<<(int)(SZ_GATE/ 8 / 256), blk, 0, stream>>>(gate_w, gaH, (int)(SZ_GATE / 8));
        wcvt_k<<<(int)(SZ_W1  / 8 / 256), blk, 0, stream>>>(w1, w1H, (int)(SZ_W1 / 8));
        wcvt_k<<<(int)(SZ_W1  / 8 / 256), blk, 0, stream>>>(w2, w2H, (int)(SZ_W1 / 8));
        wcvt_k<<<(int)(SZ_W1  / 8 / 256), blk, 0, stream>>>(w3, w3H, (int)(SZ_W1 / 8));
    }

    // 1. h = rmsnorm(x) -> P0 pair
    rmsnorm_k<0><<<Mrows, blk, 0, stream>>>(x, nullptr, nullptr, norm1_w, P0h, P0l);
    // 2. conv(h) -> P1 pair
    conv_k<<<Mrows, blk, 0, stream>>>(P0h, P0l, conv_w, conv_b, P1h, P1l);
    // 3. local = conv @ pw^T -> P2 pair
    launch_gemm<0>(pre, nb8, 8, stream, P1h, P1l, nu, nu, HIDc, pwH, pw_w,
                   nullptr, P2h, P2l, HIDc, HIDc, 0, nullptr, nullptr,
                   nu, nu, 0, nu, nu, 0, nu, nu, 0);
    // 4. qkv = h @ qkv^T -> q=P1, k=P3, v=OUT pairs
    if (pre) {
        launch_gemm<5>(pre, nb24, 24, stream, P0h, P0l, nu, nu, HIDc, qkvH, qkv_w,
                       nullptr, P1h, P1l, HIDc, HIDc, 0, nullptr, nullptr,
                       P3h, P3l, HIDc, OUTh, OUTl, HIDc, nu, nu, 0);
    } else {
        launch_gemm<0>(pre, nb8, 8, stream, P0h, P0l, nu, nu, HIDc, qkvH, qkv_w,
                       nullptr, P1h, P1l, HIDc, HIDc, 0, nullptr, nullptr,
                       nu, nu, 0, nu, nu, 0, nu, nu, 0);
        launch_gemm<0>(pre, nb8, 8, stream, P0h, P0l, nu, nu, HIDc, qkvH + SZ_SQ, qkv_w + SZ_SQ,
                       nullptr, P3h, P3l, HIDc, HIDc, 0, nullptr, nullptr,
                       nu, nu, 0, nu, nu, 0, nu, nu, 0);
        launch_gemm<0>(pre, nb8, 8, stream, P0h, P0l, nu, nu, HIDc, qkvH + 2 * SZ_SQ, qkv_w + 2 * SZ_SQ,
                       nullptr, OUTh, OUTl, HIDc, HIDc, 0, nullptr, nullptr,
                       nu, nu, 0, nu, nu, 0, nu, nu, 0);
    }
    // 5a. local scans: skv over k (P3, in place); sks -> P0
    scan1_k<<<Bc * NHc * NC, dim3(64), 0, stream>>>(P3h, P3l, OUTh, OUTl, P0h, P0l, decay_param);
    // 5b. carry + output: o over q (P1, in place)
    scan2_k<<<Bc * NHc * NC, dim3(64), 0, stream>>>(P1h, P1l, P3h, P3l, P0h, P0l, decay_param);
    // 6. out-gate -> P0 pair
    launch_gemm<3>(pre, nb8, 8, stream, P1h, P1l, nu, nu, HIDc, ogH, out_gate_w,
                   nullptr, P0h, P0l, HIDc, HIDc, 0, out_gate_b, nullptr,
                   P1h, P1l, HIDc, OUTh, OUTl, HIDc, nu, nu, 0);
    // 7. attn = o2 @ op^T -> P3 pair
    launch_gemm<0>(pre, nb8, 8, stream, P0h, P0l, nu, nu, HIDc, opH, out_proj_w,
                   nullptr, P3h, P3l, HIDc, HIDc, 0, nullptr, nullptr,
                   nu, nu, 0, nu, nu, 0, nu, nu, 0);
    // 8. gate fusion -> P0 pair (x1)
    launch_gemm<4>(pre, nb8, 8, stream, P2h, P2l, P3h, P3l, HIDc, gaH, gate_w,
                   nullptr, P0h, P0l, HIDc, 2 * HIDc, HIDc, nullptr, x,
                   nu, nu, HIDc, P2h, P2l, HIDc, P3h, P3l, HIDc);
    // 9. h2 = rmsnorm(x1) -> OUT pair (scratch)
    rmsnorm_k<1><<<Mrows, blk, 0, stream>>>(nullptr, P0h, P0l, norm2_w, OUTh, OUTl);
    // 10+11. u = silu(h2@w1^T) * (h2@w2^T) -> T1 pair (fused SwiGLU)
    if (pre) {
        gemm_dual_k<<<dim3(nb22), blk, 0, stream>>>(OUTh, OUTl, HIDc, w1H, w2H,
                                                    T1h, T1l, INTERc, HIDc, 22);
    } else {
        launch_gemm<1>(pre, nb22, 22, stream, OUTh, OUTl, nu, nu, HIDc, w1H, w1,
                       nullptr, T1h, T1l, INTERc, HIDc, 0, nullptr, nullptr,
                       nu, nu, 0, nu, nu, 0, nu, nu, 0);
        launch_gemm<2>(pre, nb22, 22, stream, OUTh, OUTl, nu, nu, HIDc, w2H, w2,
                       nullptr, T1h, T1l, INTERc, HIDc, 0, nullptr, nullptr,
                       nu, nu, 0, nu, nu, 0, nu, nu, 0);
    }
    // 12. OUT = x1 + u @ w3^T  (fp32 out to d_out)
    launch_gemm<6>(pre, nb8, 8, stream, T1h, T1l, nu, nu, INTERc, w3H, w3,
                   OUT, P0h, P0l, HIDc, INTERc, 0, nullptr, nullptr,
                   nu, nu, 0, nu, nu, 0, nu, nu, 0);
}